// Round 1
// baseline (2646.036 us; speedup 1.0000x reference)
//
#include <hip/hip_runtime.h>
#include <cstdint>
#include <cstddef>

// Problem constants (from reference): B=4, H=16, S=2048, DK=64
#define Bb 4
#define Hh 16
#define Ss 2048
#define Dk 64
#define BQ 16          // query rows per block
#define BK 128         // key tile
#define NT (Ss / BK)   // 16 k-tiles

// Fused attention: per block = one (b,h) and a strip of BQ query rows.
// Phase A: scores = mask ? -1e9 : (Q K^T)/8, written raw into attn output
//          region (acts as scratch; strip stays L2-hot), row-max tracked.
// Phase B: row-sum of exp(s - m) (re-reads own raw scores).
// Phase C: p = exp(s-m)/l -> final attn write + LDS stage; out += p V.
__global__ __launch_bounds__(256)
void attn_fused(const float* __restrict__ Qg, const float* __restrict__ Kg,
                const float* __restrict__ Vg, const unsigned char* __restrict__ Mg,
                float* __restrict__ outg, float* __restrict__ attng) {
    __shared__ float Qs[BQ][Dk + 1];    // stride 65: conflict-free Qs[qi][d]
    __shared__ float Ks[BK][Dk + 1];    // stride 65: K tile (reused for V)
    __shared__ float Ps[BQ][BK + 1];    // stride 129: p tile for PV GEMM
    __shared__ float red[BQ][17];       // row-stat partials
    __shared__ float rowm[BQ], rowinv[BQ];
    __shared__ int mflag_s;

    const int tid = threadIdx.x;
    const int bid = blockIdx.x;
    const int qb  = bid & (Ss / BQ - 1);   // 0..127  (fastest -> K/V L2 reuse)
    const int bh  = bid >> 7;              // 0..63
    const int b   = bh >> 4;

    // ---- mask element-width detection (bool(1B) vs int32(4B)) ----
    // int32 0/1 masks have zero bytes at offsets i%4!=0; random bool does not.
    int f = 0;
    for (int i = tid; i < 4096; i += 256)
        if ((i & 3) && Mg[i]) f = 1;
    if (tid == 0) mflag_s = 0;
    __syncthreads();
    if (f) mflag_s = 1;          // benign same-value race
    __syncthreads();
    const int mstride = mflag_s ? 1 : 4;

    const int qi  = tid & 15;    // 0..15 query row within strip
    const int khi = tid >> 4;    // 0..15 key-group / out-col-group
    const size_t q = (size_t)qb * BQ + qi;

    const float* Qb = Qg + (size_t)bh * Ss * Dk;
    const float* Kb = Kg + (size_t)bh * Ss * Dk;
    const float* Vb = Vg + (size_t)bh * Ss * Dk;
    float* Arow = attng + ((size_t)bh * Ss + q) * Ss;
    const unsigned char* Mrow = Mg + (size_t)mstride * (((size_t)b * Ss + q) * Ss);

    // ---- stage Q strip ----
    for (int i = tid; i < BQ * Dk; i += 256)
        Qs[i >> 6][i & 63] = Qb[(size_t)qb * BQ * Dk + i];

    // ---- Phase A: scores + row-max ----
    float tmax = -3.0e38f;
    for (int kt = 0; kt < NT; ++kt) {
        __syncthreads();
        const float* Kt = Kb + (size_t)kt * BK * Dk;
        for (int i = tid; i < BK * Dk; i += 256)
            Ks[i >> 6][i & 63] = Kt[i];
        __syncthreads();

        float acc[8] = {0.f, 0.f, 0.f, 0.f, 0.f, 0.f, 0.f, 0.f};
        #pragma unroll 8
        for (int d = 0; d < Dk; ++d) {
            float qv = Qs[qi][d];
            #pragma unroll
            for (int j = 0; j < 8; ++j)
                acc[j] += qv * Ks[khi * 8 + j][d];
        }
        const int k0 = kt * BK + khi * 8;
        #pragma unroll
        for (int j = 0; j < 8; ++j) {
            int k = k0 + j;
            float s = Mrow[(size_t)mstride * k] ? -1.0e9f : acc[j] * 0.125f;
            Arow[k] = s;
            tmax = fmaxf(tmax, s);
        }
    }

    // ---- row-max reduce across the 16 khi owners of each row ----
    __syncthreads();
    red[qi][khi] = tmax;
    __syncthreads();
    if (tid < BQ) {
        float m = -3.0e38f;
        #pragma unroll
        for (int i = 0; i < 16; ++i) m = fmaxf(m, red[tid][i]);
        rowm[tid] = m;
    }
    __syncthreads();
    const float m = rowm[qi];

    // ---- Phase B: row-sum ----
    float tsum = 0.f;
    for (int kt = 0; kt < NT; ++kt) {
        const int k0 = kt * BK + khi * 8;
        #pragma unroll
        for (int j = 0; j < 8; ++j)
            tsum += __expf(Arow[k0 + j] - m);
    }
    __syncthreads();
    red[qi][khi] = tsum;
    __syncthreads();
    if (tid < BQ) {
        float ssum = 0.f;
        #pragma unroll
        for (int i = 0; i < 16; ++i) ssum += red[tid][i];
        rowinv[tid] = 1.0f / ssum;
    }
    __syncthreads();
    const float rinv = rowinv[qi];

    // ---- Phase C: final attn write + out = P V ----
    const int dg = khi;            // out columns d = dg*4 .. dg*4+3
    float acc_o[4] = {0.f, 0.f, 0.f, 0.f};
    for (int kt = 0; kt < NT; ++kt) {
        __syncthreads();           // protect Ks(V) + Ps from prior iter reads
        const float* Vt = Vb + (size_t)kt * BK * Dk;
        for (int i = tid; i < BK * Dk; i += 256)
            Ks[i >> 6][i & 63] = Vt[i];
        const int k0 = kt * BK + khi * 8;
        #pragma unroll
        for (int j = 0; j < 8; ++j) {
            int k = k0 + j;
            float p = __expf(Arow[k] - m) * rinv;
            Arow[k] = p;                    // final attn value
            Ps[qi][khi * 8 + j] = p;
        }
        __syncthreads();
        #pragma unroll 4
        for (int k = 0; k < BK; ++k) {
            float pv = Ps[qi][k];
            #pragma unroll
            for (int jj = 0; jj < 4; ++jj)
                acc_o[jj] += pv * Ks[k][dg * 4 + jj];
        }
    }

    float* Orow = outg + ((size_t)bh * Ss + q) * Dk + dg * 4;
    #pragma unroll
    for (int jj = 0; jj < 4; ++jj) Orow[jj] = acc_o[jj];
}

extern "C" void kernel_launch(void* const* d_in, const int* in_sizes, int n_in,
                              void* d_out, int out_size, void* d_ws, size_t ws_size,
                              hipStream_t stream) {
    const float* Q = (const float*)d_in[0];
    const float* K = (const float*)d_in[1];
    const float* V = (const float*)d_in[2];
    const unsigned char* M = (const unsigned char*)d_in[3];
    float* out  = (float*)d_out;
    float* attn = out + (size_t)Bb * Hh * Ss * Dk;   // outputs concatenated

    dim3 grid(Bb * Hh * (Ss / BQ));
    attn_fused<<<grid, 256, 0, stream>>>(Q, K, V, M, out, attn);
}

// Round 2
// 559.696 us; speedup vs baseline: 4.7276x; 4.7276x over previous
//
#include <hip/hip_runtime.h>
#include <cstdint>
#include <cstddef>

// Problem: B=4, H=16, S=2048, DK=64; out = (attn@V, attn), fp32.
#define S_LEN 2048
#define DKD   64
#define BQ    64
#define BK    128
#define NKT   16          // S/BK
#define BDIM  256

typedef float f32x4 __attribute__((ext_vector_type(4)));
typedef short s16x8 __attribute__((ext_vector_type(8)));
typedef short s16x4 __attribute__((ext_vector_type(4)));

// ---- LDS layout (bytes). 53,248 total -> 3 blocks/CU. ----
#define KS_STRIDE 144                    // 72 bf16/row: row-stride 36 dw (=4 mod 32) -> <=2-way b128 reads
#define KS_OFF    0
#define KS_SIZE   (BK * KS_STRIDE)       // 18432
#define QS_OFF    KS_SIZE                // Q strip (dead after a-frag load) overlaps Vt
#define VT_OFF    KS_SIZE
#define VT_STRIDE 272                    // 136 bf16: V^T rows (dv), cols k
#define VT_SIZE   (DKD * VT_STRIDE)      // 17408
#define PS_OFF    (VT_OFF + VT_SIZE)     // 35840: P tile [64 q][BK k] bf16, stride 272
#define PS_STRIDE 272
#define PS_SIZE   (BQ * PS_STRIDE)       // 17408
#define SMEM_SZ   (PS_OFF + PS_SIZE)     // 53248

__device__ __forceinline__ unsigned short f2bf(float f) {  // RNE fp32->bf16
  unsigned u = __builtin_bit_cast(unsigned, f);
  return (unsigned short)((u + 0x7FFFu + ((u >> 16) & 1u)) >> 16);
}

// ---------- kernel0: pack mask -> 1 bit per element into ws ----------
__global__ __launch_bounds__(256)
void pack_mask(const unsigned char* __restrict__ Mg, unsigned long long* __restrict__ bits) {
  __shared__ int mflag_s;
  const int tid = threadIdx.x;
  int f = 0;                                   // bool(1B) vs int32(4B) detection
  for (int i = tid; i < 4096; i += 256) if ((i & 3) && Mg[i]) f = 1;
  if (tid == 0) mflag_s = 0;
  __syncthreads();
  if (f) mflag_s = 1;
  __syncthreads();
  const int mstride = mflag_s ? 1 : 4;

  const int row = blockIdx.x * 8 + (tid >> 5);     // 8192 rows (b*S+q)
  const int wd  = tid & 31;                        // 32 u64 words per row
  const size_t kbase = (size_t)row * S_LEN + (size_t)wd * 64;
  unsigned long long word = 0;
  if (mstride == 1) {
    const unsigned long long* p = (const unsigned long long*)(Mg + kbase);
    #pragma unroll
    for (int i = 0; i < 8; ++i) {
      unsigned long long x = p[i];
      unsigned long long nz = x | (x >> 4); nz |= nz >> 2; nz |= nz >> 1;
      nz &= 0x0101010101010101ull;
      word |= ((nz * 0x0102040810204080ull) >> 56) << (8 * i);   // movemask, carry-free
    }
  } else {
    const unsigned* p = (const unsigned*)Mg + kbase;
    #pragma unroll
    for (int i = 0; i < 64; ++i) word |= (unsigned long long)(p[i] ? 1u : 0u) << i;
  }
  bits[(size_t)row * 32 + wd] = word;
}

// ---------- kernel0b: V fp32 [bh][k][dv] -> bf16 V^T [bh][dv][k] in ws ----------
__global__ __launch_bounds__(256)
void transpose_v(const float* __restrict__ Vg, unsigned short* __restrict__ VtG) {
  __shared__ float scr[64][65];
  const int tid = threadIdx.x;
  const int bh = blockIdx.x >> 5, kb = blockIdx.x & 31;   // 64-row k-tile
  const float4* src = (const float4*)(Vg + ((size_t)bh * S_LEN + (size_t)kb * 64) * DKD);
  #pragma unroll
  for (int it = 0; it < 4; ++it) {
    int c = tid + 256 * it;               // kr = c>>4, d0 = 4*(c&15)
    float4 v = src[c];
    int kr = c >> 4, d0 = (c & 15) * 4;
    scr[kr][d0 + 0] = v.x; scr[kr][d0 + 1] = v.y; scr[kr][d0 + 2] = v.z; scr[kr][d0 + 3] = v.w;
  }
  __syncthreads();
  #pragma unroll
  for (int it = 0; it < 4; ++it) {
    int c = tid + 256 * it;               // dv = c>>4, k0 = 4*(c&15)
    int dv = c >> 4, k0 = (c & 15) * 4;
    ushort4 h = make_ushort4(f2bf(scr[k0 + 0][dv]), f2bf(scr[k0 + 1][dv]),
                             f2bf(scr[k0 + 2][dv]), f2bf(scr[k0 + 3][dv]));
    *(ushort4*)(VtG + ((size_t)bh * DKD + dv) * S_LEN + (size_t)kb * 64 + k0) = h;
  }
}

// ---------- fused attention: MODE 1 = ws (bits + pre-transposed V), MODE 0 = self-contained ----------
template <int MODE>
__global__ __launch_bounds__(256)
void attn_fused(const float* __restrict__ Qg, const float* __restrict__ Kg,
                const float* __restrict__ Vg, const unsigned char* __restrict__ Mg,
                const unsigned long long* __restrict__ bits,
                const unsigned short* __restrict__ VtG,
                float* __restrict__ outg, float* __restrict__ attng) {
  __shared__ char smem[SMEM_SZ];
  __shared__ int mflag_s;

  const int tid = threadIdx.x;
  // XCD swizzle: blocks of one bh stay on one XCD, qb fastest (K/V stays L2-hot)
  const int p = blockIdx.x;
  const int qb = (p >> 3) & 31;
  const int bh = (p & 7) + 8 * (p >> 8);
  const int b  = bh >> 4;

  int mstride = 1;
  if constexpr (MODE == 0) {
    int f = 0;
    for (int i = tid; i < 4096; i += BDIM) if ((i & 3) && Mg[i]) f = 1;
    if (tid == 0) mflag_s = 0;
    __syncthreads();
    if (f) mflag_s = 1;
    __syncthreads();
    mstride = mflag_s ? 1 : 4;
  }

  const int lane = tid & 63, wv = tid >> 6;
  const int cl = lane & 15, g = lane >> 4;
  const int q0 = qb * BQ + 16 * wv + 4 * g;       // C-layout rows of this lane (q0..q0+3)

  const float* Kbh = Kg + (size_t)bh * S_LEN * DKD;
  const float* Vbh = Vg + (size_t)bh * S_LEN * DKD;
  const unsigned short* Vtbh = (MODE == 1) ? (VtG + (size_t)bh * DKD * S_LEN) : nullptr;

  // per-lane row pointers
  float* aRow[4]; float* oRow[4];
  const unsigned char* mRow[4];
  const unsigned long long* bitRow[4];
  #pragma unroll
  for (int r = 0; r < 4; ++r) {
    aRow[r] = attng + (size_t)(bh * S_LEN + q0 + r) * S_LEN + cl;
    oRow[r] = outg + (size_t)(bh * S_LEN + q0 + r) * DKD + cl;
    if constexpr (MODE == 0)
      mRow[r] = Mg + ((size_t)(b * S_LEN + q0 + r) * S_LEN + cl) * (size_t)mstride;
    else
      bitRow[r] = bits + (size_t)(b * S_LEN + q0 + r) * 32;
  }

  // ---- stage Q strip (bf16) ----
  {
    const float4* qsrc = (const float4*)(Qg + ((size_t)bh * S_LEN + (size_t)qb * BQ) * DKD);
    #pragma unroll
    for (int it = 0; it < 4; ++it) {
      int c = tid + BDIM * it;
      float4 v = qsrc[c];
      *(ushort4*)(smem + QS_OFF + (c >> 4) * KS_STRIDE + (c & 15) * 8) =
          make_ushort4(f2bf(v.x), f2bf(v.y), f2bf(v.z), f2bf(v.w));
    }
  }

  s16x8 aq0, aq1;
  float mreg[4], lreg[4], rinv[4];
  #pragma unroll
  for (int r = 0; r < 4; ++r) { mreg[r] = -1e30f; lreg[r] = 0.f; }

  // ================= phase 1: online (m,l) =================
  for (int kt = 0; kt < NKT; ++kt) {
    const float4* ksrc = (const float4*)(Kbh + (size_t)kt * (BK * DKD));
    #pragma unroll
    for (int it = 0; it < 8; ++it) {
      int c = tid + BDIM * it;
      float4 v = ksrc[c];
      *(ushort4*)(smem + KS_OFF + (c >> 4) * KS_STRIDE + (c & 15) * 8) =
          make_ushort4(f2bf(v.x), f2bf(v.y), f2bf(v.z), f2bf(v.w));
    }
    __syncthreads();
    if (kt == 0) {
      aq0 = *(const s16x8*)(smem + QS_OFF + (16 * wv + cl) * KS_STRIDE + 16 * g);
      aq1 = *(const s16x8*)(smem + QS_OFF + (16 * wv + cl) * KS_STRIDE + 64 + 16 * g);
    }
    f32x4 accs[8];
    #pragma unroll
    for (int s = 0; s < 8; ++s) {
      s16x8 b0 = *(const s16x8*)(smem + KS_OFF + (16 * s + cl) * KS_STRIDE + 16 * g);
      s16x8 b1 = *(const s16x8*)(smem + KS_OFF + (16 * s + cl) * KS_STRIDE + 64 + 16 * g);
      f32x4 acc = {0.f, 0.f, 0.f, 0.f};
      acc = __builtin_amdgcn_mfma_f32_16x16x32_bf16(aq0, b0, acc, 0, 0, 0);
      acc = __builtin_amdgcn_mfma_f32_16x16x32_bf16(aq1, b1, acc, 0, 0, 0);
      accs[s] = acc;
    }
    // mask source for this k-tile
    unsigned long long bw0[4], bw1[4];
    const unsigned char* mkt[4];
    #pragma unroll
    for (int r = 0; r < 4; ++r) {
      if constexpr (MODE == 1) { bw0[r] = bitRow[r][2 * kt]; bw1[r] = bitRow[r][2 * kt + 1]; }
      else                     { mkt[r] = mRow[r] + (size_t)(kt * BK) * mstride; }
    }
    #pragma unroll
    for (int r = 0; r < 4; ++r) {
      float vv[8]; float tm = mreg[r];
      #pragma unroll
      for (int s = 0; s < 8; ++s) {
        bool mk;
        if constexpr (MODE == 1) {
          unsigned long long wsel = (s < 4) ? bw0[r] : bw1[r];
          mk = (wsel >> ((16 * s + cl) & 63)) & 1ull;
        } else {
          mk = mkt[r][(size_t)(16 * s) * mstride] != 0;
        }
        float sc = mk ? -1e30f : accs[s][r] * 0.125f;   // scores/sqrt(64); masked -> -inf-ish
        vv[s] = sc; tm = fmaxf(tm, sc);
      }
      float sum = 0.f;
      #pragma unroll
      for (int s = 0; s < 8; ++s) sum += __expf(vv[s] - tm);
      lreg[r] = lreg[r] * __expf(mreg[r] - tm) + sum;
      mreg[r] = tm;
    }
    __syncthreads();
  }

  // merge (m,l) across the 16 column-lanes sharing the same rows
  #pragma unroll
  for (int r = 0; r < 4; ++r) {
    #pragma unroll
    for (int d = 1; d < 16; d <<= 1) {
      float mo = __shfl_xor(mreg[r], d);
      float lo = __shfl_xor(lreg[r], d);
      float mn = fmaxf(mreg[r], mo);
      lreg[r] = lreg[r] * __expf(mreg[r] - mn) + lo * __expf(mo - mn);
      mreg[r] = mn;
    }
    rinv[r] = 1.f / lreg[r];
  }

  // ================= phase 2: recompute, write attn, PV =================
  f32x4 accpv[4];
  #pragma unroll
  for (int db = 0; db < 4; ++db) accpv[db] = (f32x4){0.f, 0.f, 0.f, 0.f};

  for (int kt = 0; kt < NKT; ++kt) {
    {   // stage K
      const float4* ksrc = (const float4*)(Kbh + (size_t)kt * (BK * DKD));
      #pragma unroll
      for (int it = 0; it < 8; ++it) {
        int c = tid + BDIM * it;
        float4 v = ksrc[c];
        *(ushort4*)(smem + KS_OFF + (c >> 4) * KS_STRIDE + (c & 15) * 8) =
            make_ushort4(f2bf(v.x), f2bf(v.y), f2bf(v.z), f2bf(v.w));
      }
    }
    if constexpr (MODE == 1) {   // stage V^T from pre-transposed bf16 (coalesced)
      #pragma unroll
      for (int it = 0; it < 8; ++it) {
        int c = tid + BDIM * it;                 // dv = c>>5, kcol = 4*(c&31)
        int dv = c >> 5, kc = (c & 31) * 4;
        ushort4 h = *(const ushort4*)(Vtbh + (size_t)dv * S_LEN + (size_t)kt * BK + kc);
        *(ushort4*)(smem + VT_OFF + dv * VT_STRIDE + kc * 2) = h;
      }
    } else {                     // fallback: scatter-transpose fp32 V in-block
      const float4* vsrc = (const float4*)(Vbh + (size_t)kt * (BK * DKD));
      #pragma unroll
      for (int it = 0; it < 8; ++it) {
        int c = tid + BDIM * it;
        float4 v = vsrc[c];
        int k = c >> 4, d0 = (c & 15) * 4;
        *(unsigned short*)(smem + VT_OFF + (d0 + 0) * VT_STRIDE + k * 2) = f2bf(v.x);
        *(unsigned short*)(smem + VT_OFF + (d0 + 1) * VT_STRIDE + k * 2) = f2bf(v.y);
        *(unsigned short*)(smem + VT_OFF + (d0 + 2) * VT_STRIDE + k * 2) = f2bf(v.z);
        *(unsigned short*)(smem + VT_OFF + (d0 + 3) * VT_STRIDE + k * 2) = f2bf(v.w);
      }
    }
    __syncthreads();

    unsigned long long bw0[4], bw1[4];
    const unsigned char* mkt[4];
    #pragma unroll
    for (int r = 0; r < 4; ++r) {
      if constexpr (MODE == 1) { bw0[r] = bitRow[r][2 * kt]; bw1[r] = bitRow[r][2 * kt + 1]; }
      else                     { mkt[r] = mRow[r] + (size_t)(kt * BK) * mstride; }
    }

    #pragma unroll
    for (int ks = 0; ks < 4; ++ks) {       // 32 k-cols per step
      f32x4 qa[2];
      #pragma unroll
      for (int sp = 0; sp < 2; ++sp) {
        int s = 2 * ks + sp;
        s16x8 b0 = *(const s16x8*)(smem + KS_OFF + (16 * s + cl) * KS_STRIDE + 16 * g);
        s16x8 b1 = *(const s16x8*)(smem + KS_OFF + (16 * s + cl) * KS_STRIDE + 64 + 16 * g);
        f32x4 acc = {0.f, 0.f, 0.f, 0.f};
        acc = __builtin_amdgcn_mfma_f32_16x16x32_bf16(aq0, b0, acc, 0, 0, 0);
        acc = __builtin_amdgcn_mfma_f32_16x16x32_bf16(aq1, b1, acc, 0, 0, 0);
        qa[sp] = acc;
      }
      #pragma unroll
      for (int sp = 0; sp < 2; ++sp) {
        int s = 2 * ks + sp;
        #pragma unroll
        for (int r = 0; r < 4; ++r) {
          bool mk;
          if constexpr (MODE == 1) {
            unsigned long long wsel = (s < 4) ? bw0[r] : bw1[r];
            mk = (wsel >> ((16 * s + cl) & 63)) & 1ull;
          } else {
            mk = mkt[r][(size_t)(16 * s) * mstride] != 0;
          }
          float sc = mk ? -1e30f : qa[sp][r] * 0.125f;
          float pv = __expf(sc - mreg[r]) * rinv[r];
          __builtin_nontemporal_store(pv, aRow[r] + kt * BK + 16 * s);
          *(unsigned short*)(smem + PS_OFF + (16 * wv + 4 * g + r) * PS_STRIDE +
                             (32 * ks + 16 * sp + cl) * 2) = f2bf(pv);
        }
      }
      // PV: A = P (rows q via cl), B = V^T rows dv; sigma = {4g+j, 16+4g+j} on both sides
      s16x4 p0 = *(const s16x4*)(smem + PS_OFF + (16 * wv + cl) * PS_STRIDE + (32 * ks + 4 * g) * 2);
      s16x4 p1 = *(const s16x4*)(smem + PS_OFF + (16 * wv + cl) * PS_STRIDE + (32 * ks + 16 + 4 * g) * 2);
      s16x8 pa = __builtin_shufflevector(p0, p1, 0, 1, 2, 3, 4, 5, 6, 7);
      #pragma unroll
      for (int db = 0; db < 4; ++db) {
        s16x4 v0 = *(const s16x4*)(smem + VT_OFF + (16 * db + cl) * VT_STRIDE + (32 * ks + 4 * g) * 2);
        s16x4 v1 = *(const s16x4*)(smem + VT_OFF + (16 * db + cl) * VT_STRIDE + (32 * ks + 16 + 4 * g) * 2);
        s16x8 vb = __builtin_shufflevector(v0, v1, 0, 1, 2, 3, 4, 5, 6, 7);
        accpv[db] = __builtin_amdgcn_mfma_f32_16x16x32_bf16(pa, vb, accpv[db], 0, 0, 0);
      }
    }
    __syncthreads();
  }

  #pragma unroll
  for (int db = 0; db < 4; ++db)
    #pragma unroll
    for (int r = 0; r < 4; ++r)
      oRow[r][16 * db] = accpv[db][r];
}

extern "C" void kernel_launch(void* const* d_in, const int* in_sizes, int n_in,
                              void* d_out, int out_size, void* d_ws, size_t ws_size,
                              hipStream_t stream) {
  const float* Q = (const float*)d_in[0];
  const float* K = (const float*)d_in[1];
  const float* V = (const float*)d_in[2];
  const unsigned char* M = (const unsigned char*)d_in[3];
  float* out = (float*)d_out;
  float* attn = out + (size_t)4 * 16 * S_LEN * DKD;   // outputs concatenated (out, attn)

  const size_t BITS_SZ = (size_t)4 * S_LEN * 32 * 8;            // 2 MB
  const size_t VT_SZ = (size_t)64 * DKD * S_LEN * 2;            // 16 MB
  if (ws_size >= BITS_SZ + VT_SZ) {
    unsigned long long* bits = (unsigned long long*)d_ws;
    unsigned short* VtG = (unsigned short*)((char*)d_ws + BITS_SZ);
    pack_mask<<<1024, 256, 0, stream>>>(M, bits);
    transpose_v<<<2048, 256, 0, stream>>>(V, VtG);
    attn_fused<1><<<2048, BDIM, 0, stream>>>(Q, K, V, M, bits, VtG, out, attn);
  } else {
    attn_fused<0><<<2048, BDIM, 0, stream>>>(Q, K, V, M, nullptr, nullptr, out, attn);
  }
}

// Round 3
// 365.981 us; speedup vs baseline: 7.2300x; 1.5293x over previous
//
#include <hip/hip_runtime.h>
#include <cstdint>
#include <cstddef>

// Problem: B=4, H=16, S=2048, DK=64; out = (attn@V, attn), fp32.
#define S_LEN 2048
#define DKD   64
#define BQ    64
#define BK    128
#define NKT   16
#define BDIM  256

typedef float f32x4 __attribute__((ext_vector_type(4)));
typedef short s16x8 __attribute__((ext_vector_type(8)));
typedef short s16x4 __attribute__((ext_vector_type(4)));
typedef unsigned short u16t;
typedef unsigned long long u64t;

// ---- LDS layout for attn_ws (bytes) ----
#define KS_OFF    0
#define KT_BYTES  (BK * DKD * 2)              // 16384, linear rows of 128B
#define VT_OFF    16384
#define VT_BYTES  (DKD * BK * 2)              // 16384, linear rows of 256B
#define PS_OFF    32768
#define PS_STRIDE 264                          // 264B rows: 8g bank spread on writes
#define SMEM_SZ   (PS_OFF + BQ * PS_STRIDE)   // 49664 -> 3 blocks/CU

__device__ __forceinline__ u16t f2bf(float f) {  // RNE fp32->bf16
  unsigned u = __builtin_bit_cast(unsigned, f);
  return (u16t)((u + 0x7FFFu + ((u >> 16) & 1u)) >> 16);
}

__device__ __forceinline__ void gl_lds16(const void* g, void* l) {
  typedef __attribute__((address_space(1))) void gvoid;
  typedef __attribute__((address_space(3))) void lvoid;
  __builtin_amdgcn_global_load_lds((gvoid*)(void*)g, (lvoid*)l, 16, 0, 0);
}

// ---------- pack mask -> 1 bit per element ----------
__global__ __launch_bounds__(256)
void pack_mask(const unsigned char* __restrict__ Mg, u64t* __restrict__ bits) {
  __shared__ int mflag_s;
  const int tid = threadIdx.x;
  int f = 0;                                   // bool(1B) vs int32(4B) detection
  for (int i = tid; i < 4096; i += 256) if ((i & 3) && Mg[i]) f = 1;
  if (tid == 0) mflag_s = 0;
  __syncthreads();
  if (f) mflag_s = 1;
  __syncthreads();
  const int mstride = mflag_s ? 1 : 4;

  const int row = blockIdx.x * 8 + (tid >> 5);     // 8192 rows (b*S+q)
  const int wd  = tid & 31;
  const size_t kbase = (size_t)row * S_LEN + (size_t)wd * 64;
  u64t word = 0;
  if (mstride == 1) {
    const u64t* p = (const u64t*)(Mg + kbase);
    #pragma unroll
    for (int i = 0; i < 8; ++i) {
      u64t x = p[i];
      u64t nz = x | (x >> 4); nz |= nz >> 2; nz |= nz >> 1;
      nz &= 0x0101010101010101ull;
      word |= ((nz * 0x0102040810204080ull) >> 56) << (8 * i);
    }
  } else {
    const unsigned* p = (const unsigned*)Mg + kbase;
    #pragma unroll
    for (int i = 0; i < 64; ++i) word |= (u64t)(p[i] ? 1u : 0u) << i;
  }
  bits[(size_t)row * 32 + wd] = word;
}

// ---------- K fp32 -> bf16 tiles [bh][kt][128 rows][64], 16B-chunk XOR-permuted ----------
__global__ __launch_bounds__(256)
void conv_k(const float* __restrict__ Kg, u16t* __restrict__ Kws) {
  const int tid = threadIdx.x;
  const int bh = blockIdx.x >> 4, kt = blockIdx.x & 15;
  const float* src = Kg + ((size_t)bh * S_LEN + (size_t)kt * BK) * DKD;
  u16t* dst = Kws + (size_t)blockIdx.x * (BK * DKD);
  #pragma unroll
  for (int i = 0; i < 4; ++i) {
    int c = tid + 256 * i;                 // 1024 chunks of 8 elems (16B)
    int row = c >> 3, y = c & 7;
    int oc = y ^ (row & 7);                // ws[row][y] = K[row][chunk y^(row&7)]
    const float4* s4 = (const float4*)(src + row * DKD + 8 * oc);
    float4 a = s4[0], b = s4[1];
    s16x8 h = { (short)f2bf(a.x), (short)f2bf(a.y), (short)f2bf(a.z), (short)f2bf(a.w),
                (short)f2bf(b.x), (short)f2bf(b.y), (short)f2bf(b.z), (short)f2bf(b.w) };
    *(s16x8*)(dst + row * DKD + 8 * y) = h;
  }
}

// ---------- V fp32 [k][dv] -> bf16 V^T tiles [bh][kt][64 dv][128 k], 8B-chunk XOR-permuted ----------
__global__ __launch_bounds__(256)
void conv_v(const float* __restrict__ Vg, u16t* __restrict__ Vws) {
  __shared__ float scr[BK][DKD + 1];
  const int tid = threadIdx.x;
  const float4* src = (const float4*)(Vg + (size_t)blockIdx.x * (BK * DKD));
  #pragma unroll
  for (int i = 0; i < 8; ++i) {
    int c = tid + 256 * i;
    float4 v = src[c];
    int k = c >> 4, d0 = (c & 15) * 4;
    scr[k][d0] = v.x; scr[k][d0 + 1] = v.y; scr[k][d0 + 2] = v.z; scr[k][d0 + 3] = v.w;
  }
  __syncthreads();
  u16t* dst = Vws + (size_t)blockIdx.x * (DKD * BK);
  #pragma unroll
  for (int i = 0; i < 8; ++i) {
    int c = tid + 256 * i;                 // 2048 chunks of 4 elems (8B)
    int dv = c >> 5, y = c & 31;
    int k0 = 4 * (y ^ (dv & 7));           // ws[dv][y] = Vt[dv][chunk y^(dv&7)]
    ushort4 h = make_ushort4(f2bf(scr[k0][dv]), f2bf(scr[k0 + 1][dv]),
                             f2bf(scr[k0 + 2][dv]), f2bf(scr[k0 + 3][dv]));
    *(ushort4*)(dst + dv * BK + 4 * y) = h;
  }
}

// ---------- fused attention, ws path ----------
__global__ __launch_bounds__(256)
void attn_ws(const float* __restrict__ Qg, const u16t* __restrict__ Kws,
             const u16t* __restrict__ Vws, const u64t* __restrict__ bits,
             float* __restrict__ outg, float* __restrict__ attng) {
  __shared__ char smem[SMEM_SZ];
  const int tid = threadIdx.x;
  const int p = blockIdx.x;
  const int qb = (p >> 3) & 31;                 // XCD swizzle: bh pinned per XCD
  const int bh = (p & 7) + 8 * (p >> 8);
  const int b  = bh >> 4;
  const int lane = tid & 63, wv = tid >> 6;
  const int cl = lane & 15, g = lane >> 4;
  const int q0 = qb * BQ + 16 * wv + 4 * g;     // C rows of this lane: q0..q0+3
  const int swzK = (cl & 7) << 4;               // read-side XOR, 16B chunks
  const int swzV = (cl & 7) << 3;               // read-side XOR, 8B chunks

  const char* Kbh = (const char*)Kws + (size_t)bh * NKT * KT_BYTES;
  const char* Vbh = (const char*)Vws + (size_t)bh * NKT * VT_BYTES;

  float* aRow[4]; float* oRow[4]; const u64t* bitRow[4];
  #pragma unroll
  for (int r = 0; r < 4; ++r) {
    aRow[r] = attng + (size_t)(bh * S_LEN + q0 + r) * S_LEN + cl;
    oRow[r] = outg  + (size_t)(bh * S_LEN + q0 + r) * DKD + cl;
    bitRow[r] = bits + (size_t)(b * S_LEN + q0 + r) * 32;
  }

  // A fragments straight from fp32 Q (one-time)
  s16x8 aq0, aq1;
  {
    const float* qrow = Qg + ((size_t)bh * S_LEN + qb * BQ + 16 * wv + cl) * DKD;
    float x[8], y[8];
    *(float4*)(x)     = *(const float4*)(qrow + 8 * g);
    *(float4*)(x + 4) = *(const float4*)(qrow + 8 * g + 4);
    *(float4*)(y)     = *(const float4*)(qrow + 32 + 8 * g);
    *(float4*)(y + 4) = *(const float4*)(qrow + 32 + 8 * g + 4);
    #pragma unroll
    for (int j = 0; j < 8; ++j) { aq0[j] = (short)f2bf(x[j]); aq1[j] = (short)f2bf(y[j]); }
  }

  auto stageK = [&](int kt) {
    const char* src = Kbh + (size_t)kt * KT_BYTES + wv * 4096 + lane * 16;
    #pragma unroll
    for (int t = 0; t < 4; ++t)
      gl_lds16(src + t * 1024, (void*)(smem + KS_OFF + wv * 4096 + t * 1024));
  };
  auto stageV = [&](int kt) {
    const char* src = Vbh + (size_t)kt * VT_BYTES + wv * 4096 + lane * 16;
    #pragma unroll
    for (int t = 0; t < 4; ++t)
      gl_lds16(src + t * 1024, (void*)(smem + VT_OFF + wv * 4096 + t * 1024));
  };

  // ================= phase 1: row-sums l (no-max softmax) =================
  float lsum[4] = {0.f, 0.f, 0.f, 0.f};
  for (int kt = 0; kt < NKT; ++kt) {
    stageK(kt);
    __syncthreads();
    f32x4 accs[8];
    #pragma unroll
    for (int s = 0; s < 8; ++s) {
      const char* rb = smem + KS_OFF + (16 * s + cl) * 128;
      s16x8 b0 = *(const s16x8*)(rb + ((16 * g) ^ swzK));
      s16x8 b1 = *(const s16x8*)(rb + ((64 + 16 * g) ^ swzK));
      f32x4 acc = {0.f, 0.f, 0.f, 0.f};
      acc = __builtin_amdgcn_mfma_f32_16x16x32_bf16(aq0, b0, acc, 0, 0, 0);
      acc = __builtin_amdgcn_mfma_f32_16x16x32_bf16(aq1, b1, acc, 0, 0, 0);
      accs[s] = acc;
    }
    u64t bw0[4], bw1[4];
    #pragma unroll
    for (int r = 0; r < 4; ++r) { bw0[r] = bitRow[r][2 * kt]; bw1[r] = bitRow[r][2 * kt + 1]; }
    #pragma unroll
    for (int r = 0; r < 4; ++r) {
      float sum = 0.f;
      #pragma unroll
      for (int s = 0; s < 8; ++s) {
        bool mk = (((s < 4) ? bw0[r] : bw1[r]) >> ((16 * s + cl) & 63)) & 1ull;
        float e = __expf(accs[s][r] * 0.125f);
        sum += mk ? 0.f : e;
      }
      lsum[r] += sum;
    }
    __syncthreads();
  }
  float rinv[4];
  #pragma unroll
  for (int r = 0; r < 4; ++r) {
    float l = lsum[r];
    #pragma unroll
    for (int d = 1; d < 16; d <<= 1) l += __shfl_xor(l, d);
    rinv[r] = 1.f / l;
  }

  // ================= phase 2: recompute, write attn, PV =================
  f32x4 accpv[4];
  #pragma unroll
  for (int db = 0; db < 4; ++db) accpv[db] = (f32x4){0.f, 0.f, 0.f, 0.f};

  for (int kt = 0; kt < NKT; ++kt) {
    stageK(kt);
    stageV(kt);
    __syncthreads();
    u64t bw0[4], bw1[4];
    #pragma unroll
    for (int r = 0; r < 4; ++r) { bw0[r] = bitRow[r][2 * kt]; bw1[r] = bitRow[r][2 * kt + 1]; }

    #pragma unroll
    for (int ks = 0; ks < 4; ++ks) {
      f32x4 qa[2];
      #pragma unroll
      for (int sp = 0; sp < 2; ++sp) {
        int s = 2 * ks + sp;
        const char* rb = smem + KS_OFF + (16 * s + cl) * 128;
        s16x8 b0 = *(const s16x8*)(rb + ((16 * g) ^ swzK));
        s16x8 b1 = *(const s16x8*)(rb + ((64 + 16 * g) ^ swzK));
        f32x4 acc = {0.f, 0.f, 0.f, 0.f};
        acc = __builtin_amdgcn_mfma_f32_16x16x32_bf16(aq0, b0, acc, 0, 0, 0);
        acc = __builtin_amdgcn_mfma_f32_16x16x32_bf16(aq1, b1, acc, 0, 0, 0);
        qa[sp] = acc;
      }
      #pragma unroll
      for (int sp = 0; sp < 2; ++sp) {
        int s = 2 * ks + sp;
        #pragma unroll
        for (int r = 0; r < 4; ++r) {
          bool mk = (((s < 4) ? bw0[r] : bw1[r]) >> ((16 * s + cl) & 63)) & 1ull;
          float pv = mk ? 0.f : __expf(qa[sp][r] * 0.125f) * rinv[r];
          __builtin_nontemporal_store(pv, aRow[r] + kt * BK + 16 * s);
          *(u16t*)(smem + PS_OFF + (16 * wv + 4 * g + r) * PS_STRIDE +
                   (32 * ks + 16 * sp + cl) * 2) = f2bf(pv);
        }
      }
      s16x4 p0 = *(const s16x4*)(smem + PS_OFF + (16 * wv + cl) * PS_STRIDE + (32 * ks + 4 * g) * 2);
      s16x4 p1 = *(const s16x4*)(smem + PS_OFF + (16 * wv + cl) * PS_STRIDE + (32 * ks + 16 + 4 * g) * 2);
      s16x8 pa = __builtin_shufflevector(p0, p1, 0, 1, 2, 3, 4, 5, 6, 7);
      #pragma unroll
      for (int db = 0; db < 4; ++db) {
        const char* vrow = smem + VT_OFF + (16 * db + cl) * 256;
        s16x4 v0 = *(const s16x4*)(vrow + ((64 * ks + 8 * g) ^ swzV));
        s16x4 v1 = *(const s16x4*)(vrow + ((64 * ks + 32 + 8 * g) ^ swzV));
        s16x8 vb = __builtin_shufflevector(v0, v1, 0, 1, 2, 3, 4, 5, 6, 7);
        accpv[db] = __builtin_amdgcn_mfma_f32_16x16x32_bf16(pa, vb, accpv[db], 0, 0, 0);
      }
    }
    __syncthreads();
  }

  #pragma unroll
  for (int db = 0; db < 4; ++db)
    #pragma unroll
    for (int r = 0; r < 4; ++r)
      oRow[r][16 * db] = accpv[db][r];
}

// ---------- fallback (self-contained, R2-proven structure) ----------
#define FB_KSTR 144
#define FB_VOFF (BK * FB_KSTR)
#define FB_VSTR 272
#define FB_POFF (FB_VOFF + DKD * FB_VSTR)
#define FB_SMEM (FB_POFF + BQ * FB_VSTR)

__global__ __launch_bounds__(256)
void attn_fb(const float* __restrict__ Qg, const float* __restrict__ Kg,
             const float* __restrict__ Vg, const unsigned char* __restrict__ Mg,
             float* __restrict__ outg, float* __restrict__ attng) {
  __shared__ char smem[FB_SMEM];
  __shared__ int mflag_s;
  const int tid = threadIdx.x;
  const int p = blockIdx.x;
  const int qb = (p >> 3) & 31;
  const int bh = (p & 7) + 8 * (p >> 8);
  const int b  = bh >> 4;

  int f = 0;
  for (int i = tid; i < 4096; i += BDIM) if ((i & 3) && Mg[i]) f = 1;
  if (tid == 0) mflag_s = 0;
  __syncthreads();
  if (f) mflag_s = 1;
  __syncthreads();
  const int mstride = mflag_s ? 1 : 4;

  const int lane = tid & 63, wv = tid >> 6;
  const int cl = lane & 15, g = lane >> 4;
  const int q0 = qb * BQ + 16 * wv + 4 * g;

  const float* Kbh = Kg + (size_t)bh * S_LEN * DKD;
  const float* Vbh = Vg + (size_t)bh * S_LEN * DKD;

  float* aRow[4]; float* oRow[4]; const unsigned char* mRow[4];
  #pragma unroll
  for (int r = 0; r < 4; ++r) {
    aRow[r] = attng + (size_t)(bh * S_LEN + q0 + r) * S_LEN + cl;
    oRow[r] = outg + (size_t)(bh * S_LEN + q0 + r) * DKD + cl;
    mRow[r] = Mg + ((size_t)(b * S_LEN + q0 + r) * S_LEN + cl) * (size_t)mstride;
  }

  s16x8 aq0, aq1;
  {
    const float* qrow = Qg + ((size_t)bh * S_LEN + qb * BQ + 16 * wv + cl) * DKD;
    float x[8], y[8];
    *(float4*)(x)     = *(const float4*)(qrow + 8 * g);
    *(float4*)(x + 4) = *(const float4*)(qrow + 8 * g + 4);
    *(float4*)(y)     = *(const float4*)(qrow + 32 + 8 * g);
    *(float4*)(y + 4) = *(const float4*)(qrow + 32 + 8 * g + 4);
    #pragma unroll
    for (int j = 0; j < 8; ++j) { aq0[j] = (short)f2bf(x[j]); aq1[j] = (short)f2bf(y[j]); }
  }

  float lsum[4] = {0.f, 0.f, 0.f, 0.f};
  for (int kt = 0; kt < NKT; ++kt) {
    const float4* ksrc = (const float4*)(Kbh + (size_t)kt * (BK * DKD));
    #pragma unroll
    for (int it = 0; it < 8; ++it) {
      int c = tid + BDIM * it;
      float4 v = ksrc[c];
      *(ushort4*)(smem + (c >> 4) * FB_KSTR + (c & 15) * 8) =
          make_ushort4(f2bf(v.x), f2bf(v.y), f2bf(v.z), f2bf(v.w));
    }
    __syncthreads();
    #pragma unroll
    for (int s = 0; s < 8; ++s) {
      s16x8 b0 = *(const s16x8*)(smem + (16 * s + cl) * FB_KSTR + 16 * g);
      s16x8 b1 = *(const s16x8*)(smem + (16 * s + cl) * FB_KSTR + 64 + 16 * g);
      f32x4 acc = {0.f, 0.f, 0.f, 0.f};
      acc = __builtin_amdgcn_mfma_f32_16x16x32_bf16(aq0, b0, acc, 0, 0, 0);
      acc = __builtin_amdgcn_mfma_f32_16x16x32_bf16(aq1, b1, acc, 0, 0, 0);
      #pragma unroll
      for (int r = 0; r < 4; ++r) {
        bool mk = mRow[r][(size_t)(kt * BK + 16 * s) * mstride] != 0;
        lsum[r] += mk ? 0.f : __expf(acc[r] * 0.125f);
      }
    }
    __syncthreads();
  }
  float rinv[4];
  #pragma unroll
  for (int r = 0; r < 4; ++r) {
    float l = lsum[r];
    #pragma unroll
    for (int d = 1; d < 16; d <<= 1) l += __shfl_xor(l, d);
    rinv[r] = 1.f / l;
  }

  f32x4 accpv[4];
  #pragma unroll
  for (int db = 0; db < 4; ++db) accpv[db] = (f32x4){0.f, 0.f, 0.f, 0.f};

  for (int kt = 0; kt < NKT; ++kt) {
    const float4* ksrc = (const float4*)(Kbh + (size_t)kt * (BK * DKD));
    #pragma unroll
    for (int it = 0; it < 8; ++it) {
      int c = tid + BDIM * it;
      float4 v = ksrc[c];
      *(ushort4*)(smem + (c >> 4) * FB_KSTR + (c & 15) * 8) =
          make_ushort4(f2bf(v.x), f2bf(v.y), f2bf(v.z), f2bf(v.w));
    }
    const float4* vsrc = (const float4*)(Vbh + (size_t)kt * (BK * DKD));
    #pragma unroll
    for (int it = 0; it < 8; ++it) {
      int c = tid + BDIM * it;
      float4 v = vsrc[c];
      int k = c >> 4, d0 = (c & 15) * 4;
      *(u16t*)(smem + FB_VOFF + (d0 + 0) * FB_VSTR + k * 2) = f2bf(v.x);
      *(u16t*)(smem + FB_VOFF + (d0 + 1) * FB_VSTR + k * 2) = f2bf(v.y);
      *(u16t*)(smem + FB_VOFF + (d0 + 2) * FB_VSTR + k * 2) = f2bf(v.z);
      *(u16t*)(smem + FB_VOFF + (d0 + 3) * FB_VSTR + k * 2) = f2bf(v.w);
    }
    __syncthreads();

    #pragma unroll
    for (int ks = 0; ks < 4; ++ks) {
      f32x4 qa[2];
      #pragma unroll
      for (int sp = 0; sp < 2; ++sp) {
        int s = 2 * ks + sp;
        s16x8 b0 = *(const s16x8*)(smem + (16 * s + cl) * FB_KSTR + 16 * g);
        s16x8 b1 = *(const s16x8*)(smem + (16 * s + cl) * FB_KSTR + 64 + 16 * g);
        f32x4 acc = {0.f, 0.f, 0.f, 0.f};
        acc = __builtin_amdgcn_mfma_f32_16x16x32_bf16(aq0, b0, acc, 0, 0, 0);
        acc = __builtin_amdgcn_mfma_f32_16x16x32_bf16(aq1, b1, acc, 0, 0, 0);
        qa[sp] = acc;
      }
      #pragma unroll
      for (int sp = 0; sp < 2; ++sp) {
        int s = 2 * ks + sp;
        #pragma unroll
        for (int r = 0; r < 4; ++r) {
          bool mk = mRow[r][(size_t)(kt * BK + 16 * s) * mstride] != 0;
          float pv = mk ? 0.f : __expf(qa[sp][r] * 0.125f) * rinv[r];
          __builtin_nontemporal_store(pv, aRow[r] + kt * BK + 16 * s);
          *(u16t*)(smem + FB_POFF + (16 * wv + 4 * g + r) * FB_VSTR +
                   (32 * ks + 16 * sp + cl) * 2) = f2bf(pv);
        }
      }
      s16x4 p0 = *(const s16x4*)(smem + FB_POFF + (16 * wv + cl) * FB_VSTR + (32 * ks + 4 * g) * 2);
      s16x4 p1 = *(const s16x4*)(smem + FB_POFF + (16 * wv + cl) * FB_VSTR + (32 * ks + 16 + 4 * g) * 2);
      s16x8 pa = __builtin_shufflevector(p0, p1, 0, 1, 2, 3, 4, 5, 6, 7);
      #pragma unroll
      for (int db = 0; db < 4; ++db) {
        s16x4 v0 = *(const s16x4*)(smem + FB_VOFF + (16 * db + cl) * FB_VSTR + (32 * ks + 4 * g) * 2);
        s16x4 v1 = *(const s16x4*)(smem + FB_VOFF + (16 * db + cl) * FB_VSTR + (32 * ks + 16 + 4 * g) * 2);
        s16x8 vb = __builtin_shufflevector(v0, v1, 0, 1, 2, 3, 4, 5, 6, 7);
        accpv[db] = __builtin_amdgcn_mfma_f32_16x16x32_bf16(pa, vb, accpv[db], 0, 0, 0);
      }
    }
    __syncthreads();
  }

  #pragma unroll
  for (int db = 0; db < 4; ++db)
    #pragma unroll
    for (int r = 0; r < 4; ++r)
      oRow[r][16 * db] = accpv[db][r];
}

extern "C" void kernel_launch(void* const* d_in, const int* in_sizes, int n_in,
                              void* d_out, int out_size, void* d_ws, size_t ws_size,
                              hipStream_t stream) {
  const float* Q = (const float*)d_in[0];
  const float* K = (const float*)d_in[1];
  const float* V = (const float*)d_in[2];
  const unsigned char* M = (const unsigned char*)d_in[3];
  float* out = (float*)d_out;
  float* attn = out + (size_t)4 * 16 * S_LEN * DKD;

  const size_t BITS_SZ = (size_t)4 * S_LEN * 32 * 8;              // 2 MB
  const size_t KWS_SZ  = (size_t)64 * NKT * BK * DKD * 2;         // 16 MB
  const size_t VWS_SZ  = (size_t)64 * NKT * DKD * BK * 2;         // 16 MB
  if (ws_size >= BITS_SZ + KWS_SZ + VWS_SZ) {
    u64t* bits = (u64t*)d_ws;
    u16t* Kws = (u16t*)((char*)d_ws + BITS_SZ);
    u16t* Vws = (u16t*)((char*)d_ws + BITS_SZ + KWS_SZ);
    pack_mask<<<1024, 256, 0, stream>>>(M, bits);
    conv_k<<<1024, 256, 0, stream>>>(K, Kws);
    conv_v<<<1024, 256, 0, stream>>>(V, Vws);
    attn_ws<<<2048, BDIM, 0, stream>>>(Q, Kws, Vws, bits, out, attn);
  } else {
    attn_fb<<<2048, BDIM, 0, stream>>>(Q, K, V, M, out, attn);
  }
}